// Round 1
// 193.809 us; speedup vs baseline: 1.0215x; 1.0215x over previous
//
#include <hip/hip_runtime.h>

// RangeLoss, R8: discriminating experiment — is stage1 overhead-bound or at BW floor?
// R7 evidence: top-5 dispatches are all harness 384MiB fills @ 84-86% HBM peak;
// stage1 < 58.5us (below top-5 cutoff). Floor for our part: 192MB reads @ 6.88TB/s
// = 28us. This round: UNROLL 2->3 (NB 12288->8192, -33% block overhead, 6
// back-to-back dwordx4/thread), nontemporal on BOTH read-once streams (keep them
// out of L2 so the next fill doesn't contend), float4 stage2. If neutral, stage1
// was already at the read floor and the remaining ~160us is harness reset => roofline.

#define N3      25165824                  // 8388608 * 3 floats
#define G4      6291456                   // N3 / 4 float4s
#define BLOCK   256
#define UNROLL  3
#define NB      (G4 / (BLOCK * UNROLL))   // 8192, exact
#define INV_TOTAL (1.0f / 25165824.0f)

typedef float vfloat4 __attribute__((ext_vector_type(4)));

__global__ void __launch_bounds__(BLOCK, 8) rangeloss_stage1(
    const vfloat4* __restrict__ preds4,
    const vfloat4* __restrict__ target4,
    const float*   __restrict__ predsf,
    float* __restrict__ partials)
{
    const int tid  = threadIdx.x;
    const int lane = tid & 63;
    const int wv   = tid >> 6;
    const int base = blockIdx.x * (BLOCK * UNROLL) + tid;

    // ---- load phase: exactly 6 dwordx4 per thread, back-to-back ----
    vfloat4 p[UNROLL], t[UNROLL];
    #pragma unroll
    for (int k = 0; k < UNROLL; ++k) {
        const int i = base + k * BLOCK;
        p[k] = __builtin_nontemporal_load(&preds4[i]);    // read-once stream
        t[k] = __builtin_nontemporal_load(&target4[i]);   // read-once stream
    }

    // block-boundary neighbor: preds element just past this block's range.
    // Only consumed by tid==BLOCK-1 at k==UNROLL-1. 1 lane, 1 line.
    float edge = 0.0f;
    if (tid == BLOCK - 1) {
        const int nf = 4 * (blockIdx.x + 1) * (BLOCK * UNROLL);
        edge = predsf[min(nf, N3 - 1)];   // clamp: global-last element is col 2, unused
    }
    __builtin_amdgcn_sched_barrier(0);

    // ---- p_next exchange (no global pn loads) ----
    // pnext(tid,k) = p.x of float4 (i+1) = p[k].x of tid+1  (tid<255)
    //             = p[k+1].x of tid 0    (tid==255, k<UNROLL-1)
    //             = edge                 (tid==255, k==UNROLL-1)
    __shared__ float xs[4][UNROLL];       // [wave][chunk], lane-0 values
    if (lane == 0) {
        #pragma unroll
        for (int k = 0; k < UNROLL; ++k) xs[wv][k] = p[k].x;
    }
    __syncthreads();

    float pn[UNROLL];
    #pragma unroll
    for (int k = 0; k < UNROLL; ++k) {
        float nx = __shfl_down(p[k].x, 1, 64);            // lanes 0..62
        if (lane == 63) {
            if (wv < 3)                nx = xs[wv + 1][k];            // next wave's lane 0
            else if (k < UNROLL - 1)   nx = xs[0][k + 1];             // tid 0, next chunk
            else                       nx = edge;                     // next block
        }
        pn[k] = nx;
    }

    // ---- compute ----
    float sum = 0.0f;
    #pragma unroll
    for (int k = 0; k < UNROLL; ++k) {
        const int i  = base + k * BLOCK;
        const int ph = i % 3;     // col of element 0 is (4i)%3 = i%3

        const float pe[4]  = {p[k].x, p[k].y, p[k].z, p[k].w};
        const float te[4]  = {t[k].x, t[k].y, t[k].z, t[k].w};
        const float pnx[4] = {p[k].y, p[k].z, p[k].w, pn[k]};

        #pragma unroll
        for (int e = 0; e < 4; ++e) {
            int col = ph + e;
            col = (col >= 3) ? col - 3 : col;             // (ph+e) mod 3
            const bool is_c1 = (col == 1);

            const float pp = pe[e], tt = te[e];
            const float diff = pp - tt;

            // col 0/2: target is exactly 0.0 or 1.0 -> snap iff |p-t| < 0.1
            const bool r02 = __builtin_fabsf(diff) < 0.1f;
            // col 1: snap iff p_next>0.9 or p*1.02>t && p*0.98<t (exact ref form)
            const bool inr = (pp * 1.02f > tt) && (pp * 0.98f < tt);
            const bool r1  = (pnx[e] > 0.9f) || inr;

            const bool snap = is_c1 ? r1 : r02;
            const float d = snap ? 0.0f : diff;           // snapped => diff exactly 0
            sum = fmaf(d, d, sum);
        }
    }

    sum *= INV_TOTAL;  // pre-scale so summed partials equal the mean

    // wave-64 butterfly reduce
    #pragma unroll
    for (int off = 32; off > 0; off >>= 1)
        sum += __shfl_down(sum, off, 64);

    __shared__ float red[BLOCK / 64];
    if (lane == 0) red[wv] = sum;
    __syncthreads();

    if (tid == 0)
        partials[blockIdx.x] = red[0] + red[1] + red[2] + red[3];
}

#define S2BLOCK 1024

__global__ void __launch_bounds__(S2BLOCK) rangeloss_stage2(
    const vfloat4* __restrict__ partials4,
    float* __restrict__ out)
{
    // NB = 8192 partials = 2048 float4s; 1024 threads x 2 vector loads
    const vfloat4 a = partials4[threadIdx.x];
    const vfloat4 b = partials4[threadIdx.x + S2BLOCK];
    float sum = (a.x + a.y) + (a.z + a.w) + (b.x + b.y) + (b.z + b.w);

    #pragma unroll
    for (int off = 32; off > 0; off >>= 1)
        sum += __shfl_down(sum, off, 64);

    __shared__ float smem[S2BLOCK / 64];
    const int lane = threadIdx.x & 63;
    const int wave = threadIdx.x >> 6;
    if (lane == 0) smem[wave] = sum;
    __syncthreads();

    if (threadIdx.x == 0) {
        float s = 0.0f;
        #pragma unroll
        for (int w = 0; w < S2BLOCK / 64; ++w) s += smem[w];
        out[0] = s;  // overwrites poison
    }
}

extern "C" void kernel_launch(void* const* d_in, const int* in_sizes, int n_in,
                              void* d_out, int out_size, void* d_ws, size_t ws_size,
                              hipStream_t stream)
{
    const vfloat4* preds4  = (const vfloat4*)d_in[0];
    const vfloat4* target4 = (const vfloat4*)d_in[1];
    const float*   predsf  = (const float*)d_in[0];
    float* partials = (float*)d_ws;   // NB floats = 32 KB, fully written by stage 1
    float* out = (float*)d_out;

    rangeloss_stage1<<<NB, BLOCK, 0, stream>>>(preds4, target4, predsf, partials);
    rangeloss_stage2<<<1, S2BLOCK, 0, stream>>>((const vfloat4*)partials, out);
}

// Round 2
// 193.421 us; speedup vs baseline: 1.0236x; 1.0020x over previous
//
#include <hip/hip_runtime.h>

// RangeLoss, R9: block-count lever, second pull.
// R8 post-mortem: -4.2us from {NB 12288->8192 + NT-on-preds}; ambiguous which
// mechanism. Timed region decomposes to ~150-160us harness fills/poison (fills
// measured 84-86% HBM peak) + ~35-40us controllable vs 28us read floor.
// This round isolates the block-count axis: BLOCK 256->512, NB 8192->4096,
// identical load/compute structure. Neutral result => lever exhausted => roofline.

#define N3      25165824                  // 8388608 * 3 floats
#define G4      6291456                   // N3 / 4 float4s
#define BLOCK   512
#define WAVES   (BLOCK / 64)              // 8
#define UNROLL  3
#define NB      (G4 / (BLOCK * UNROLL))   // 4096, exact
#define INV_TOTAL (1.0f / 25165824.0f)

typedef float vfloat4 __attribute__((ext_vector_type(4)));

__global__ void __launch_bounds__(BLOCK, 8) rangeloss_stage1(
    const vfloat4* __restrict__ preds4,
    const vfloat4* __restrict__ target4,
    const float*   __restrict__ predsf,
    float* __restrict__ partials)
{
    const int tid  = threadIdx.x;
    const int lane = tid & 63;
    const int wv   = tid >> 6;
    const int base = blockIdx.x * (BLOCK * UNROLL) + tid;

    // ---- load phase: exactly 6 dwordx4 per thread, back-to-back ----
    vfloat4 p[UNROLL], t[UNROLL];
    #pragma unroll
    for (int k = 0; k < UNROLL; ++k) {
        const int i = base + k * BLOCK;
        p[k] = __builtin_nontemporal_load(&preds4[i]);    // read-once stream
        t[k] = __builtin_nontemporal_load(&target4[i]);   // read-once stream
    }

    // block-boundary neighbor: preds element just past this block's range.
    // Only consumed by tid==BLOCK-1 at k==UNROLL-1. 1 lane, 1 line.
    float edge = 0.0f;
    if (tid == BLOCK - 1) {
        const int nf = 4 * (blockIdx.x + 1) * (BLOCK * UNROLL);
        edge = predsf[min(nf, N3 - 1)];   // clamp: global-last element is col 2, unused
    }
    __builtin_amdgcn_sched_barrier(0);

    // ---- p_next exchange (no global pn loads) ----
    // pnext(tid,k) = p.x of float4 (i+1) = p[k].x of tid+1  (tid<BLOCK-1)
    //             = p[k+1].x of tid 0    (tid==BLOCK-1, k<UNROLL-1)
    //             = edge                 (tid==BLOCK-1, k==UNROLL-1)
    __shared__ float xs[WAVES][UNROLL];   // [wave][chunk], lane-0 values
    if (lane == 0) {
        #pragma unroll
        for (int k = 0; k < UNROLL; ++k) xs[wv][k] = p[k].x;
    }
    __syncthreads();

    float pn[UNROLL];
    #pragma unroll
    for (int k = 0; k < UNROLL; ++k) {
        float nx = __shfl_down(p[k].x, 1, 64);            // lanes 0..62
        if (lane == 63) {
            if (wv < WAVES - 1)        nx = xs[wv + 1][k];            // next wave's lane 0
            else if (k < UNROLL - 1)   nx = xs[0][k + 1];             // tid 0, next chunk
            else                       nx = edge;                     // next block
        }
        pn[k] = nx;
    }

    // ---- compute ----
    float sum = 0.0f;
    #pragma unroll
    for (int k = 0; k < UNROLL; ++k) {
        const int i  = base + k * BLOCK;
        const int ph = i % 3;     // col of element 0 is (4i)%3 = i%3

        const float pe[4]  = {p[k].x, p[k].y, p[k].z, p[k].w};
        const float te[4]  = {t[k].x, t[k].y, t[k].z, t[k].w};
        const float pnx[4] = {p[k].y, p[k].z, p[k].w, pn[k]};

        #pragma unroll
        for (int e = 0; e < 4; ++e) {
            int col = ph + e;
            col = (col >= 3) ? col - 3 : col;             // (ph+e) mod 3
            const bool is_c1 = (col == 1);

            const float pp = pe[e], tt = te[e];
            const float diff = pp - tt;

            // col 0/2: target is exactly 0.0 or 1.0 -> snap iff |p-t| < 0.1
            const bool r02 = __builtin_fabsf(diff) < 0.1f;
            // col 1: snap iff p_next>0.9 or p*1.02>t && p*0.98<t (exact ref form)
            const bool inr = (pp * 1.02f > tt) && (pp * 0.98f < tt);
            const bool r1  = (pnx[e] > 0.9f) || inr;

            const bool snap = is_c1 ? r1 : r02;
            const float d = snap ? 0.0f : diff;           // snapped => diff exactly 0
            sum = fmaf(d, d, sum);
        }
    }

    sum *= INV_TOTAL;  // pre-scale so summed partials equal the mean

    // wave-64 butterfly reduce
    #pragma unroll
    for (int off = 32; off > 0; off >>= 1)
        sum += __shfl_down(sum, off, 64);

    __shared__ float red[WAVES];
    if (lane == 0) red[wv] = sum;
    __syncthreads();

    if (tid == 0) {
        float s = 0.0f;
        #pragma unroll
        for (int w = 0; w < WAVES; ++w) s += red[w];
        partials[blockIdx.x] = s;
    }
}

#define S2BLOCK 1024

__global__ void __launch_bounds__(S2BLOCK) rangeloss_stage2(
    const vfloat4* __restrict__ partials4,
    float* __restrict__ out)
{
    // NB = 4096 partials = 1024 float4s; one vector load per thread
    const vfloat4 a = partials4[threadIdx.x];
    float sum = (a.x + a.y) + (a.z + a.w);

    #pragma unroll
    for (int off = 32; off > 0; off >>= 1)
        sum += __shfl_down(sum, off, 64);

    __shared__ float smem[S2BLOCK / 64];
    const int lane = threadIdx.x & 63;
    const int wave = threadIdx.x >> 6;
    if (lane == 0) smem[wave] = sum;
    __syncthreads();

    if (threadIdx.x == 0) {
        float s = 0.0f;
        #pragma unroll
        for (int w = 0; w < S2BLOCK / 64; ++w) s += smem[w];
        out[0] = s;  // overwrites poison
    }
}

extern "C" void kernel_launch(void* const* d_in, const int* in_sizes, int n_in,
                              void* d_out, int out_size, void* d_ws, size_t ws_size,
                              hipStream_t stream)
{
    const vfloat4* preds4  = (const vfloat4*)d_in[0];
    const vfloat4* target4 = (const vfloat4*)d_in[1];
    const float*   predsf  = (const float*)d_in[0];
    float* partials = (float*)d_ws;   // NB floats = 16 KB, fully written by stage 1
    float* out = (float*)d_out;

    rangeloss_stage1<<<NB, BLOCK, 0, stream>>>(preds4, target4, predsf, partials);
    rangeloss_stage2<<<1, S2BLOCK, 0, stream>>>((const vfloat4*)partials, out);
}